// Round 1
// baseline (196.966 us; speedup 1.0000x reference)
//
#include <hip/hip_runtime.h>

#define D 256
#define D4 (D/4)        // 64 float4 per fp32 row

__device__ inline float dot4(const float4 u, const float4 v) {
    return u.x*v.x + u.y*v.y + u.z*v.z + u.w*v.w;
}

__device__ inline float wsum(float v) {
    #pragma unroll
    for (int off = 32; off > 0; off >>= 1)
        v += __shfl_xor(v, off, 64);
    return v;
}

// ---- relation prep: one wave per relation (R=1000 waves total) ----------
// Orthonormal basis + score form. score = ||sub||^2 - p~^T S p~, p~ = U sub.
// Exact for both reference branches: A = C U (Gram-Schmidt), S = C^T (2M -
// M ATA M) C (= I when det != 0). Math identical to the verified int8
// version; outputs stored in fp32.
__global__ __launch_bounds__(256) void transint_relprep(
    const float* __restrict__ heads,
    const float* __restrict__ bases,
    const int*   __restrict__ rel2head,
    const float* __restrict__ rel2mult,
    float*       __restrict__ rel_f,     // [R, 3*D] fp32 rows u0,u1,re
    float*       __restrict__ par_buf,   // [R, 4]   s00,s01,s11,-
    int R)
{
    const int r    = (blockIdx.x * blockDim.x + threadIdx.x) >> 6;
    const int lane = threadIdx.x & 63;
    if (r >= R) return;

    const int   hd   = rel2head[r];
    const float mult = rel2mult[r];
    const float4* hrow = (const float4*)(heads + (size_t)hd * D);
    const float4* arow = (const float4*)(bases + (size_t)r * 2 * D);

    float4 a0 = arow[lane];
    float4 a1 = arow[D4 + lane];
    float4 re = hrow[lane];
    re.x *= mult; re.y *= mult; re.z *= mult; re.w *= mult;

    float aa = wsum(dot4(a0, a0));
    float ab = wsum(dot4(a0, a1));
    float dd = wsum(dot4(a1, a1));

    float det = aa * dd - ab * ab;
    float m00, m01, m11;
    if (det != 0.0f) {
        float inv = 1.0f / det;
        m00 = dd * inv; m01 = -ab * inv; m11 = aa * inv;
    } else {
        float inv = 1.0f / aa;
        m00 = inv; m01 = 0.0f; m11 = inv;
    }
    // Q = 2M - M*(ATA*M)
    float t00 = aa * m00 + ab * m01;
    float t01 = aa * m01 + ab * m11;
    float t10 = ab * m00 + dd * m01;
    float t11 = ab * m01 + dd * m11;
    float q00 = 2.f * m00 - (m00 * t00 + m01 * t10);
    float q01 = 2.f * m01 - (m00 * t01 + m01 * t11);
    float q11 = 2.f * m11 - (m01 * t01 + m11 * t11);

    // Gram-Schmidt: a0 = c00 u0 ; a1 = c10 u0 + c11 u1
    float c00  = sqrtf(aa);
    float ic00 = (c00 > 0.f) ? 1.f / c00 : 0.f;
    float4 u0;
    u0.x = a0.x * ic00; u0.y = a0.y * ic00; u0.z = a0.z * ic00; u0.w = a0.w * ic00;
    float c10 = ab * ic00;
    float4 v;
    v.x = a1.x - c10 * u0.x; v.y = a1.y - c10 * u0.y;
    v.z = a1.z - c10 * u0.z; v.w = a1.w - c10 * u0.w;
    float vv   = wsum(dot4(v, v));
    float c11  = sqrtf(vv);
    float ic11 = (c11 > 0.f) ? 1.f / c11 : 0.f;
    float4 u1;
    u1.x = v.x * ic11; u1.y = v.y * ic11; u1.z = v.z * ic11; u1.w = v.w * ic11;

    // S = C^T Q C, C = [[c00,0],[c10,c11]]
    float s00 = c00*c00*q00 + 2.f*c00*c10*q01 + c10*c10*q11;
    float s01 = c00*c11*q01 + c10*c11*q11;
    float s11 = c11*c11*q11;

    float4* rf = (float4*)(rel_f + (size_t)r * 3 * D);
    rf[lane]          = u0;
    rf[D4 + lane]     = u1;
    rf[2 * D4 + lane] = re;

    if (lane == 0) {
        float* p = par_buf + (size_t)r * 4;
        p[0] = s00; p[1] = s01; p[2] = s11; p[3] = 0.f;
    }
}

// ---- main: fp32 direct gather, one sample b per 16-lane group -----------
// Lane gl owns elements {4*gl + 64*c : c=0..3} of each row: each load
// instruction is a contiguous 256B segment per group (coalesced). 28 loads
// per b issued up front for MLP; pure-fma inner loop; 4-stage butterfly.
__global__ __launch_bounds__(256) void transint_main_f32(
    const int*   __restrict__ pos_h,
    const int*   __restrict__ pos_t,
    const int*   __restrict__ pos_r,
    const int*   __restrict__ neg_h,
    const int*   __restrict__ neg_t,
    const float* __restrict__ ent,       // [E, D] fp32
    const float* __restrict__ rel_f,     // [R, 3*D] fp32
    const float* __restrict__ par_buf,   // [R, 4]
    float*       __restrict__ out,       // [2*B]
    int nB)
{
    const int wave = (blockIdx.x * blockDim.x + threadIdx.x) >> 6;
    const int lane = threadIdx.x & 63;
    const int g    = lane >> 4;
    const int gl   = lane & 15;
    const int b    = wave * 4 + g;
    if (b >= nB) return;

    const int r = pos_r[b];
    const float4* ph = (const float4*)ent + (size_t)pos_h[b] * D4;
    const float4* pt = (const float4*)ent + (size_t)pos_t[b] * D4;
    const float4* nh = (const float4*)ent + (size_t)neg_h[b] * D4;
    const float4* nt = (const float4*)ent + (size_t)neg_t[b] * D4;
    const float4* rb = (const float4*)rel_f + (size_t)r * (3 * D4);

    float4 H[4], T[4], X[4], Y[4], U0[4], U1[4], RE[4];
    #pragma unroll
    for (int c = 0; c < 4; ++c) {
        const int fi = gl + 16 * c;
        H[c]  = ph[fi];
        T[c]  = pt[fi];
        X[c]  = nh[fi];
        Y[c]  = nt[fi];
        U0[c] = rb[fi];
        U1[c] = rb[D4 + fi];
        RE[c] = rb[2 * D4 + fi];
    }

    float pp0 = 0.f, pp1 = 0.f, ssp = 0.f;
    float pn0 = 0.f, pn1 = 0.f, ssn = 0.f;

    #pragma unroll
    for (int c = 0; c < 4; ++c) {
        #define ACC(comp) {                                   \
            float ps = H[c].comp - T[c].comp + RE[c].comp;    \
            float ns = X[c].comp - Y[c].comp + RE[c].comp;    \
            pp0 = fmaf(U0[c].comp, ps, pp0);                  \
            pp1 = fmaf(U1[c].comp, ps, pp1);                  \
            ssp = fmaf(ps, ps, ssp);                          \
            pn0 = fmaf(U0[c].comp, ns, pn0);                  \
            pn1 = fmaf(U1[c].comp, ns, pn1);                  \
            ssn = fmaf(ns, ns, ssn); }
        ACC(x) ACC(y) ACC(z) ACC(w)
        #undef ACC
    }

    // 4-stage butterfly within the 16-lane group
    #pragma unroll
    for (int off = 8; off > 0; off >>= 1) {
        pp0 += __shfl_xor(pp0, off, 64);
        pp1 += __shfl_xor(pp1, off, 64);
        ssp += __shfl_xor(ssp, off, 64);
        pn0 += __shfl_xor(pn0, off, 64);
        pn1 += __shfl_xor(pn1, off, 64);
        ssn += __shfl_xor(ssn, off, 64);
    }

    if (gl == 0) {
        const float* par = par_buf + (size_t)r * 4;
        const float s00 = par[0], s01 = par[1], s11 = par[2];
        out[b]      = ssp - (s00*pp0*pp0 + 2.f*s01*pp0*pp1 + s11*pp1*pp1);
        out[nB + b] = ssn - (s00*pn0*pn0 + 2.f*s01*pn0*pn1 + s11*pn1*pn1);
    }
}

extern "C" void kernel_launch(void* const* d_in, const int* in_sizes, int n_in,
                              void* d_out, int out_size, void* d_ws, size_t ws_size,
                              hipStream_t stream) {
    const int*   pos_h    = (const int*)  d_in[0];
    const int*   pos_t    = (const int*)  d_in[1];
    const int*   pos_r    = (const int*)  d_in[2];
    const int*   neg_h    = (const int*)  d_in[3];
    const int*   neg_t    = (const int*)  d_in[4];
    // d_in[5] = neg_r (unused by reference scores)
    const float* ent_emb  = (const float*)d_in[6];
    const float* heads    = (const float*)d_in[7];
    const float* bases    = (const float*)d_in[8];
    const int*   rel2head = (const int*)  d_in[9];
    const float* rel2mult = (const float*)d_in[10];
    float* out = (float*)d_out;

    const int nB = in_sizes[0];               // 65536
    const int R  = in_sizes[9];               // 1000

    // ws layout: rel_f (R*3*D*4 B = 3.07 MB) | par (R*16 B)
    float* rel_f   = (float*)d_ws;
    float* par_buf = rel_f + (size_t)R * 3 * D;

    // relation prep: R waves (4 per 256-thread block)
    {
        dim3 grid((R + 3) / 4);
        transint_relprep<<<grid, dim3(256), 0, stream>>>(
            heads, bases, rel2head, rel2mult, rel_f, par_buf, R);
    }
    // main: 4 samples per wave, 16 per 256-thread block
    {
        dim3 grid((nB + 15) / 16);
        transint_main_f32<<<grid, dim3(256), 0, stream>>>(
            pos_h, pos_t, pos_r, neg_h, neg_t,
            ent_emb, rel_f, par_buf, out, nB);
    }
}